// Round 12
// baseline (4200.728 us; speedup 1.0000x reference)
//
#include <hip/hip_runtime.h>
#include <hip/hip_cooperative_groups.h>

namespace cg = cooperative_groups;

#define B_    64
#define Q_    16
#define MAXK_ 32
#define C_    64
#define D_    768
#define H_    512
#define G4_   2048   // 4*H
#define S_    529    // Q*(MAXK+1)+1
#define NR_   81     // 16 questions + 64 code + 1 text

typedef float f32x4_t __attribute__((ext_vector_type(4)));
typedef unsigned int u32x2_t __attribute__((ext_vector_type(2)));
typedef unsigned int u32x4_t __attribute__((ext_vector_type(4)));
typedef _Float16 f16x8_t __attribute__((ext_vector_type(8)));

// ---------------- workspace layout (bytes) ----------------
static constexpr size_t OFF_L     = 0;                      // 64 int
static constexpr size_t OFF_MAXL  = 256;
static constexpr size_t OFF_MAP   = 512;                    // 64*529*4
static constexpr size_t OFF_BIAS0 = OFF_MAP   + 135424;     // 2048 f
static constexpr size_t OFF_BIAS1 = OFF_BIAS0 + 8192;       // 2048 f
static constexpr size_t OFF_C0    = OFF_BIAS1 + 8192;       // 64*512 f
static constexpr size_t OFF_C1    = OFF_C0    + 131072;
static constexpr size_t OFF_HLAST = OFF_C1    + 131072;     // 64*512 f (fp32, real-batch idx)
static constexpr size_t OFF_H0B   = OFF_HLAST + 131072;     // 2 x 64*512 half (sorted idx)
static constexpr size_t OFF_H1B   = OFF_H0B   + 262144;
static constexpr size_t OFF_WTIH0 = OFF_H1B   + 262144;     // 768x2048 f
static constexpr size_t OFF_XPROJ = OFF_WTIH0 + 6291456ULL; // 64*81*2048 f
static constexpr size_t OFF_BAR   = OFF_XPROJ + 42467328ULL; // 4 groups x 64 int (4 wave-counters x 16)
static constexpr size_t OFF_ORD   = OFF_BAR   + 4096;       // 64 int (sorted batch ids)
static constexpr size_t OFF_GMAX  = OFF_ORD   + 256;        // 4 int (per-group max L)
static constexpr size_t WS_NEED   = OFF_GMAX  + 256;

// group g owns sorted ranks [gbase, gbase+16)
__device__ __forceinline__ int group_base(int g) {
  return (g == 0) ? 0 : (g == 1) ? 16 : (g == 2) ? 48 : 32;
}

// ---------------- coherent (L2-bypass) access helpers ----------------
__device__ __forceinline__ void store_us_cc(ushort* p, unsigned int v) {
  asm volatile("global_store_short %0, %1, off sc0 sc1" :: "v"(p), "v"(v) : "memory");
}
__device__ __forceinline__ void store_f_cc(float* p, float v) {
  asm volatile("global_store_dword %0, %1, off sc0 sc1" :: "v"(p), "v"(v) : "memory");
}
__device__ __forceinline__ void load_a_cc(u32x4_t& v, const ushort* p) {
  asm volatile("global_load_dwordx4 %0, %1, off sc0 sc1" : "=v"(v) : "v"(p) : "memory");
}

__device__ __forceinline__ unsigned int pkrtz(float a, float b) {
  auto r = __builtin_amdgcn_cvt_pkrtz(a, b);
  unsigned int u;
  __builtin_memcpy(&u, &r, 4);
  return u;
}
__device__ __forceinline__ unsigned int f2h(float a) {
  return pkrtz(a, 0.f) & 0xffffu;
}
__device__ __forceinline__ f32x4_t mfma16(u32x4_t a, u32x4_t b, f32x4_t c) {
  f16x8_t av, bv;
  __builtin_memcpy(&av, &a, 16);
  __builtin_memcpy(&bv, &b, 16);
  return __builtin_amdgcn_mfma_f32_16x16x32_f16(av, bv, c, 0, 0, 0);
}

__device__ __forceinline__ float sigm(float x) { return 1.f/(1.f + __expf(-x)); }
// fast tanh: 1 - 2/(e^{2x}+1); correct limits (x->+inf: e->inf -> 1; x->-inf: -> -1)
__device__ __forceinline__ float tanh_fast(float x) {
  return 1.f - 2.f/(__expf(2.f*x) + 1.f);
}

// P-partials LDS geometry: P[wl=wv*2+layer][col=64][m=16] with col stride 20
#define PSEG 1280              // 64*20 floats per wl
#define PCOL 20

// ---------------- prep ----------------
__global__ __launch_bounds__(256) void k_prep(
    const int* __restrict__ ns, const int* __restrict__ que,
    const float* __restrict__ b_ih0, const float* __restrict__ b_hh0,
    const float* __restrict__ b_ih1, const float* __restrict__ b_hh1,
    int* __restrict__ Lp, int* __restrict__ maxLp, int* __restrict__ map,
    float* __restrict__ bias0, float* __restrict__ bias1,
    float* __restrict__ c0, float* __restrict__ c1, float* __restrict__ hlast,
    ushort* __restrict__ h0b, ushort* __restrict__ h1b, int* __restrict__ bar,
    int* __restrict__ ord, int* __restrict__ gmax)
{
  const int tid = threadIdx.x;
  for (int i = tid; i < B_*S_; i += 256) map[i] = -1;
  for (int i = tid; i < G4_; i += 256) {
    bias0[i] = b_ih0[i] + b_hh0[i];
    bias1[i] = b_ih1[i] + b_hh1[i];
  }
  int* h0i = (int*)h0b;
  int* h1i = (int*)h1b;
  for (int i = tid; i < B_*H_; i += 256) {
    c0[i]=0.f; c1[i]=0.f; hlast[i]=0.f;
    h0i[i]=0; h1i[i]=0;
  }
  for (int i = tid; i < 1024; i += 256) bar[i] = 0;
  if (tid == 0) *maxLp = 0;
  __syncthreads();
  if (tid < B_) {
    const int b = tid;
    const int qn = que[b];
    int pos = 0;
    int* m = map + b*S_;
    for (int q = 0; q < qn; ++q) {
      m[pos++] = q;
      const int n = ns[b*Q_ + q];
      for (int k = 0; k < n; ++k) {
        int j = q + k; if (j > C_-1) j = C_-1;
        m[pos++] = 16 + j;
      }
    }
    m[pos] = 80;
    Lp[b] = pos;
    atomicMax(maxLp, pos);
  }
  __syncthreads();
  if (tid < B_) {
    const int myL = Lp[tid];
    int rank = 0;
    for (int j = 0; j < B_; ++j) {
      const int lj = Lp[j];
      rank += (lj > myL) || (lj == myL && j < tid);
    }
    ord[rank] = tid;
  }
  __syncthreads();
  if (tid < 4) {
    const int gb = (tid == 0) ? 0 : (tid == 1) ? 16 : (tid == 2) ? 48 : 32;
    gmax[tid] = Lp[ord[gb]];
  }
}

// ---------------- transpose W_ih0 only ----------------
__global__ __launch_bounds__(256) void k_transpose(
    const float* __restrict__ w, float* __restrict__ wT)
{
  __shared__ float tile[32][33];
  const int n0 = blockIdx.x * 32;
  const int k0 = blockIdx.y * 32;
  const int tx = threadIdx.x, ty = threadIdx.y;
  for (int i = ty; i < 32; i += 8)
    tile[i][tx] = w[(size_t)(n0+i)*D_ + k0 + tx];
  __syncthreads();
  for (int i = ty; i < 32; i += 8)
    wT[(size_t)(k0 + i)*G4_ + n0 + tx] = tile[tx][i];
}

// ---------------- xproj ----------------
__global__ __launch_bounds__(128, 2) void k_proj(
    const float* __restrict__ text, const float* __restrict__ ques,
    const float* __restrict__ code, const float* __restrict__ wT_ih0,
    const float* __restrict__ bias0, float* __restrict__ xproj)
{
  __shared__ float hsLds[32][64];
  const int mb = blockIdx.x, nb = blockIdx.y;
  const int n0 = nb * 128;
  const int tid = threadIdx.x;
  const int tb = tid >> 4, tn = tid & 15;
  const int b0 = tb * 8;
  const int bb = tid >> 1, hh = tid & 1;

  const int mrow = mb*64 + bb;
  const int sb = mrow / NR_, sr = mrow % NR_;
  const float* srcrow = (sr < 16) ? (ques + ((size_t)sb*Q_ + sr)*D_)
                      : (sr < 80) ? (code + ((size_t)sb*C_ + (sr-16))*D_)
                                  : (text + (size_t)sb*D_);

  float a[8][8];
  #pragma unroll
  for (int i=0;i<8;i++)
    #pragma unroll
    for (int j=0;j<8;j++) a[i][j]=0.f;

  for (int k0 = 0; k0 < D_; k0 += 32) {
    __syncthreads();
    {
      const float* p = srcrow + k0 + hh*16;
      float4 v0 = *(const float4*)(p+0);
      float4 v1 = *(const float4*)(p+4);
      float4 v2 = *(const float4*)(p+8);
      float4 v3 = *(const float4*)(p+12);
      const int kk = hh*16;
      hsLds[kk+ 0][bb]=v0.x; hsLds[kk+ 1][bb]=v0.y; hsLds[kk+ 2][bb]=v0.z; hsLds[kk+ 3][bb]=v0.w;
      hsLds[kk+ 4][bb]=v1.x; hsLds[kk+ 5][bb]=v1.y; hsLds[kk+ 6][bb]=v1.z; hsLds[kk+ 7][bb]=v1.w;
      hsLds[kk+ 8][bb]=v2.x; hsLds[kk+ 9][bb]=v2.y; hsLds[kk+10][bb]=v2.z; hsLds[kk+11][bb]=v2.w;
      hsLds[kk+12][bb]=v3.x; hsLds[kk+13][bb]=v3.y; hsLds[kk+14][bb]=v3.z; hsLds[kk+15][bb]=v3.w;
    }
    __syncthreads();
    const float* wb = wT_ih0 + (size_t)k0*G4_ + n0 + tn*8;
    #pragma unroll 4
    for (int k=0;k<32;k++){
      float4 w0 = *(const float4*)(wb + (size_t)k*G4_);
      float4 w1 = *(const float4*)(wb + (size_t)k*G4_ + 4);
      float4 hA = *(const float4*)(&hsLds[k][b0]);
      float4 hB = *(const float4*)(&hsLds[k][b0+4]);
      float hv[8]={hA.x,hA.y,hA.z,hA.w,hB.x,hB.y,hB.z,hB.w};
      float wv[8]={w0.x,w0.y,w0.z,w0.w,w1.x,w1.y,w1.z,w1.w};
      #pragma unroll
      for (int i=0;i<8;i++)
        #pragma unroll
        for (int j=0;j<8;j++)
          a[i][j] = fmaf(hv[i], wv[j], a[i][j]);
    }
  }
  float bz[8];
  #pragma unroll
  for (int j=0;j<8;j++) bz[j] = bias0[n0 + tn*8 + j];
  #pragma unroll
  for (int i=0;i<8;i++){
    const int m = mb*64 + b0 + i;
    float* pd = xproj + (size_t)m*G4_ + n0 + tn*8;
    *(float4*)(pd+0) = make_float4(a[i][0]+bz[0], a[i][1]+bz[1], a[i][2]+bz[2], a[i][3]+bz[3]);
    *(float4*)(pd+4) = make_float4(a[i][4]+bz[4], a[i][5]+bz[5], a[i][6]+bz[6], a[i][7]+bz[7]);
  }
}

// ---------------- persistent LSTM (MFMA core, fat blocks) ----------------
// 128 blocks: g = blk>>5, us = blk&31 (16 units -> N=64 cols/layer).
__device__ __forceinline__ void load_wfrags(int tid, int us,
    const float* __restrict__ w_hh0, const float* __restrict__ w_ih1,
    const float* __restrict__ w_hh1, u32x4_t* wf0, u32x4_t* wf1)
{
  const int wv = tid >> 6, lane = tid & 63;
  const int nidx = lane & 15, kgrp = lane >> 4;
  #pragma unroll
  for (int nt = 0; nt < 4; ++nt) {
    const int ngl = (nidx >> 2)*H_ + us*16 + nt*4 + (nidx & 3);
    const float* r0 = w_hh0 + (size_t)ngl*H_ + wv*128 + kgrp*8;
    #pragma unroll
    for (int f = 0; f < 4; ++f) {
      float4 lo = *(const float4*)(r0 + f*32);
      float4 hi = *(const float4*)(r0 + f*32 + 4);
      wf0[nt*4+f] = (u32x4_t){pkrtz(lo.x,lo.y), pkrtz(lo.z,lo.w), pkrtz(hi.x,hi.y), pkrtz(hi.z,hi.w)};
    }
    const float* w1 = (wv < 2) ? w_ih1 : w_hh1;
    const float* r1 = w1 + (size_t)ngl*H_ + (wv & 1)*256 + kgrp*8;
    #pragma unroll
    for (int f = 0; f < 8; ++f) {
      float4 lo = *(const float4*)(r1 + f*32);
      float4 hi = *(const float4*)(r1 + f*32 + 4);
      wf1[nt*8+f] = (u32x4_t){pkrtz(lo.x,lo.y), pkrtz(lo.z,lo.w), pkrtz(hi.x,hi.y), pkrtz(hi.z,hi.w)};
    }
  }
}

__device__ __forceinline__ void xg_prefetch(int t, int maxLg,
    const int* __restrict__ mrow, const float* __restrict__ xbase,
    float& xg0, float& xg1, float& xg2, float& xg3, int& rpre)
{
  rpre = (t <= maxLg) ? mrow[t] : -1;
  const float* xp = xbase + (size_t)(rpre < 0 ? 0 : rpre)*G4_;
  xg0 = xp[0]; xg1 = xp[512]; xg2 = xp[1024]; xg3 = xp[1536];
}

__device__ __forceinline__ void lstm_iter(int t, int maxLg, int gbase, int us,
    const u32x4_t* wf0, const u32x4_t* wf1, float* __restrict__ P,
    const ushort* __restrict__ h0c, ushort* __restrict__ h0n,
    const ushort* __restrict__ h1c, ushort* __restrict__ h1n,
    float* __restrict__ c0, float* __restrict__ c1, float* __restrict__ hlast,
    const int* __restrict__ mrow, const float* __restrict__ xbase,
    float& xg0, float& xg1, float& xg2, float& xg3, int& rpre0, int& rpre1,
    float b1v0, float b1v1, float b1v2, float b1v3, int Lrb, int rb)
{
  const int tid = threadIdx.x;
  const int wv = tid >> 6, lane = tid & 63;
  const int nidx = lane & 15, kgrp = lane >> 4;

  // ---- A-fragment loads (h through LLC), first thing after release ----
  u32x4_t a0[4], a1[8];
  {
    const ushort* h0r = h0c + (size_t)(gbase + nidx)*H_ + wv*128 + kgrp*8;
    #pragma unroll
    for (int f = 0; f < 4; ++f) load_a_cc(a0[f], h0r + f*32);
    const ushort* hs1 = (wv < 2) ? h0c : h1c;
    const ushort* h1r = hs1 + (size_t)(gbase + nidx)*H_ + (wv & 1)*256 + kgrp*8;
    #pragma unroll
    for (int f = 0; f < 8; ++f) load_a_cc(a1[f], h1r + f*32);
  }
  asm volatile("s_waitcnt vmcnt(0)" ::: "memory");
  __builtin_amdgcn_sched_barrier(0);   // rule #18: keep MFMAs below the wait

  f32x4_t acc0[4], acc1[4];
  #pragma unroll
  for (int nt = 0; nt < 4; ++nt) { acc0[nt] = (f32x4_t){0.f,0.f,0.f,0.f}; acc1[nt] = (f32x4_t){0.f,0.f,0.f,0.f}; }
  #pragma unroll
  for (int nt = 0; nt < 4; ++nt)
    #pragma unroll
    for (int f = 0; f < 4; ++f) acc0[nt] = mfma16(a0[f], wf0[nt*4+f], acc0[nt]);
  #pragma unroll
  for (int nt = 0; nt < 4; ++nt)
    #pragma unroll
    for (int f = 0; f < 8; ++f) acc1[nt] = mfma16(a1[f], wf1[nt*8+f], acc1[nt]);

  // ---- stash per-wave partials ----
  #pragma unroll
  for (int nt = 0; nt < 4; ++nt) {
    *(f32x4_t*)(P + (wv*2+0)*PSEG + (nt*16 + nidx)*PCOL + kgrp*4) = acc0[nt];
    *(f32x4_t*)(P + (wv*2+1)*PSEG + (nt*16 + nidx)*PCOL + kgrp*4) = acc1[nt];
  }

  // ---- prefetch NEXT step's gate context (off critical path) ----
  float nxg0=xg0, nxg1=xg1, nxg2=xg2, nxg3=xg3;
  int nr0 = -1;
  const int nr1 = rpre0;
  xg_prefetch(t + 1, maxLg, mrow, xbase, nxg0, nxg1, nxg2, nxg3, nr0);
  __syncthreads();     // the ONE block-wide sync per iter (P cross-wave reduce)

  // ---- gates: every thread does one L0 cell and one L1 cell ----
  const int bl = tid & 15, ul = tid >> 4;
  const int pb = gbase + bl;
  const int u = us*16 + ul;
  const int idx = pb*H_ + u;
  const int clb = (ul >> 2)*16 + (ul & 3);
  if (rpre0 >= 0) {
    float g0=xg0, g1=xg1, g2=xg2, g3=xg3;
    #pragma unroll
    for (int w = 0; w < 4; ++w) {
      const float* Pr = P + (w*2+0)*PSEG + bl;
      g0 += Pr[(clb+ 0)*PCOL]; g1 += Pr[(clb+ 4)*PCOL];
      g2 += Pr[(clb+ 8)*PCOL]; g3 += Pr[(clb+12)*PCOL];
    }
    const float cc = sigm(g1)*c0[idx] + sigm(g0)*tanh_fast(g2);
    c0[idx] = cc;
    store_us_cc(h0n + idx, f2h(sigm(g3)*tanh_fast(cc)));
  }
  if (rpre1 >= 0) {
    float g0=b1v0, g1=b1v1, g2=b1v2, g3=b1v3;
    #pragma unroll
    for (int w = 0; w < 4; ++w) {
      const float* Pr = P + (w*2+1)*PSEG + bl;
      g0 += Pr[(clb+ 0)*PCOL]; g1 += Pr[(clb+ 4)*PCOL];
      g2 += Pr[(clb+ 8)*PCOL]; g3 += Pr[(clb+12)*PCOL];
    }
    const float cc = sigm(g1)*c1[idx] + sigm(g0)*tanh_fast(g2);
    c1[idx] = cc;
    const float hn = sigm(g3)*tanh_fast(cc);
    store_us_cc(h1n + idx, f2h(hn));
    if (t - 1 == Lrb) store_f_cc(hlast + rb*H_ + u, hn);
  }

  xg0 = nxg0; xg1 = nxg1; xg2 = nxg2; xg3 = nxg3;
  rpre0 = nr0; rpre1 = nr1;
}

// ---------------- per-group WAVE-level barrier: 4 counters, no syncthreads ----------------
// counters at cnt4[wv*16]; each counts 32 wave-arrivals (1 per block) per generation.
__device__ __forceinline__ void wave_barrier_g(int* __restrict__ cnt4, int gen)
{
  asm volatile("s_waitcnt vmcnt(0)" ::: "memory");   // drain this wave's sc stores
  const int wv = threadIdx.x >> 6;
  if ((threadIdx.x & 63) == 0)
    atomicAdd(cnt4 + wv*16, 1);
  const int thr = gen*32;
  for (;;) {
    const int v0 = __hip_atomic_load(cnt4 +  0, __ATOMIC_RELAXED, __HIP_MEMORY_SCOPE_AGENT);
    const int v1 = __hip_atomic_load(cnt4 + 16, __ATOMIC_RELAXED, __HIP_MEMORY_SCOPE_AGENT);
    const int v2 = __hip_atomic_load(cnt4 + 32, __ATOMIC_RELAXED, __HIP_MEMORY_SCOPE_AGENT);
    const int v3 = __hip_atomic_load(cnt4 + 48, __ATOMIC_RELAXED, __HIP_MEMORY_SCOPE_AGENT);
    if (v0 >= thr && v1 >= thr && v2 >= thr && v3 >= thr) break;
    __builtin_amdgcn_s_sleep(1);
  }
}

// ---------------- cooperative persistent kernel ----------------
__global__ __launch_bounds__(256, 1) void k_lstm_coop(
    const float* __restrict__ w_hh0, const float* __restrict__ w_ih1,
    const float* __restrict__ w_hh1, const float* __restrict__ xproj,
    const float* __restrict__ bias1, const int* __restrict__ Lp,
    const int* __restrict__ gmax, const int* __restrict__ map,
    const int* __restrict__ ord,
    ushort* __restrict__ h0b, ushort* __restrict__ h1b,
    float* __restrict__ c0, float* __restrict__ c1, float* __restrict__ hlast,
    const float* __restrict__ fcw, const float* __restrict__ fcb,
    float* __restrict__ out, int* __restrict__ bar)
{
  __shared__ __align__(16) float P[8*PSEG];
  const int blk = blockIdx.x;
  const int g = blk >> 5, us = blk & 31;
  const int gbase = group_base(g);
  const int tid = threadIdx.x;

  u32x4_t wf0[16], wf1[32];
  load_wfrags(tid, us, w_hh0, w_ih1, w_hh1, wf0, wf1);
  const int maxLg = gmax[g];
  int* cnt4 = bar + g*64;

  const int rb = ord[gbase + (tid & 15)];
  const int* mrow = map + rb*S_;
  const int u = us*16 + (tid >> 4);
  const float* xbase = xproj + (size_t)rb*NR_*G4_ + u;
  const float b1v0 = bias1[u], b1v1 = bias1[512+u], b1v2 = bias1[1024+u], b1v3 = bias1[1536+u];
  const int Lrb = Lp[rb];

  float xg0=0.f, xg1=0.f, xg2=0.f, xg3=0.f;
  int rpre0 = -1, rpre1 = -1;
  xg_prefetch(0, maxLg, mrow, xbase, xg0, xg1, xg2, xg3, rpre0);
  __syncthreads();

  for (int t = 0; t <= maxLg + 1; ++t) {
    const ushort* h0c = h0b + (size_t)(t & 1)*(B_*H_);
    ushort*       h0n = h0b + (size_t)((t+1) & 1)*(B_*H_);
    const ushort* h1c = h1b + (size_t)(t & 1)*(B_*H_);
    ushort*       h1n = h1b + (size_t)((t+1) & 1)*(B_*H_);
    lstm_iter(t, maxLg, gbase, us, wf0, wf1, P,
              h0c, h0n, h1c, h1n, c0, c1, hlast,
              mrow, xbase, xg0, xg1, xg2, xg3, rpre0, rpre1,
              b1v0, b1v1, b1v2, b1v3, Lrb, rb);
    wave_barrier_g(cnt4, t + 1);
  }
  __syncthreads();
  // ---- per-group FC epilogue ----
  if (us == 0 && tid < 32) {
    const int pb = gbase + (tid >> 1), half = tid & 1;
    const int rbf = ord[pb];
    const float* hv = hlast + (size_t)rbf*H_ + half*256;
    const float* fw = fcw + half*256;
    float s = 0.f;
    #pragma unroll 8
    for (int uu = 0; uu < 256; ++uu) s = fmaf(hv[uu], fw[uu], s);
    s += __shfl_xor(s, 1);
    if (half == 0) store_f_cc(out + rbf, s + fcb[0]);
  }
}

// ---------------- non-cooperative fallback: one iteration per launch ----------------
__global__ __launch_bounds__(256, 1) void k_step(int t,
    const float* __restrict__ w_hh0, const float* __restrict__ w_ih1,
    const float* __restrict__ w_hh1, const float* __restrict__ xproj,
    const float* __restrict__ bias1, const int* __restrict__ Lp,
    const int* __restrict__ gmax, const int* __restrict__ map,
    const int* __restrict__ ord,
    ushort* __restrict__ h0b, ushort* __restrict__ h1b,
    float* __restrict__ c0, float* __restrict__ c1, float* __restrict__ hlast)
{
  __shared__ __align__(16) float P[8*PSEG];
  const int blk = blockIdx.x;
  const int g = blk >> 5, us = blk & 31;
  const int gbase = group_base(g);
  const int maxLg = gmax[g];
  if (t > maxLg + 1) return;
  const int tid = threadIdx.x;
  u32x4_t wf0[16], wf1[32];
  load_wfrags(tid, us, w_hh0, w_ih1, w_hh1, wf0, wf1);

  const int rb = ord[gbase + (tid & 15)];
  const int* mrow = map + rb*S_;
  const int u = us*16 + (tid >> 4);
  const float* xbase = xproj + (size_t)rb*NR_*G4_ + u;
  const float b1v0 = bias1[u], b1v1 = bias1[512+u], b1v2 = bias1[1024+u], b1v3 = bias1[1536+u];
  const int Lrb = Lp[rb];

  float xg0=0.f, xg1=0.f, xg2=0.f, xg3=0.f;
  int rpre0 = -1, rpre1 = -1;
  xg_prefetch(t, maxLg, mrow, xbase, xg0, xg1, xg2, xg3, rpre0);
  rpre1 = (t-1 >= 0 && t-1 <= maxLg) ? mrow[t-1] : -1;
  __syncthreads();

  const ushort* h0c = h0b + (size_t)(t & 1)*(B_*H_);
  ushort*       h0n = h0b + (size_t)((t+1) & 1)*(B_*H_);
  const ushort* h1c = h1b + (size_t)(t & 1)*(B_*H_);
  ushort*       h1n = h1b + (size_t)((t+1) & 1)*(B_*H_);
  lstm_iter(t, maxLg, gbase, us, wf0, wf1, P,
            h0c, h0n, h1c, h1n, c0, c1, hlast,
            mrow, xbase, xg0, xg1, xg2, xg3, rpre0, rpre1,
            b1v0, b1v1, b1v2, b1v3, Lrb, rb);
}

__global__ __launch_bounds__(128) void k_fc(
    const float* __restrict__ hlast, const float* __restrict__ fcw,
    const float* __restrict__ fcb, float* __restrict__ out)
{
  const int tid = threadIdx.x;
  if (tid < 128) {
    const int b = tid >> 1, half = tid & 1;
    const float* hv = hlast + (size_t)b*H_ + half*256;
    const float* fw = fcw + half*256;
    float s = 0.f;
    #pragma unroll 8
    for (int u = 0; u < 256; ++u) s = fmaf(hv[u], fw[u], s);
    s += __shfl_xor(s, 1);
    if (half == 0) out[b] = s + fcb[0];
  }
}

// ---------------- host ----------------
extern "C" void kernel_launch(void* const* d_in, const int* in_sizes, int n_in,
                              void* d_out, int out_size, void* d_ws, size_t ws_size,
                              hipStream_t stream)
{
  const float* text  = (const float*)d_in[0];
  const float* ques  = (const float*)d_in[1];
  const float* code  = (const float*)d_in[2];
  const int*   ns    = (const int*)  d_in[3];
  const int*   que   = (const int*)  d_in[4];
  const float* w_ih0 = (const float*)d_in[5];
  const float* w_hh0 = (const float*)d_in[6];
  const float* b_ih0 = (const float*)d_in[7];
  const float* b_hh0 = (const float*)d_in[8];
  const float* w_ih1 = (const float*)d_in[9];
  const float* w_hh1 = (const float*)d_in[10];
  const float* b_ih1 = (const float*)d_in[11];
  const float* b_hh1 = (const float*)d_in[12];
  const float* fcw   = (const float*)d_in[13];
  const float* fcb   = (const float*)d_in[14];
  float* out = (float*)d_out;

  char* ws = (char*)d_ws;
  int*    Lp     = (int*)   (ws + OFF_L);
  int*    maxLp  = (int*)   (ws + OFF_MAXL);
  int*    map    = (int*)   (ws + OFF_MAP);
  float*  bias0  = (float*) (ws + OFF_BIAS0);
  float*  bias1  = (float*) (ws + OFF_BIAS1);
  float*  c0     = (float*) (ws + OFF_C0);
  float*  c1     = (float*) (ws + OFF_C1);
  float*  hlast  = (float*) (ws + OFF_HLAST);
  ushort* h0b    = (ushort*)(ws + OFF_H0B);
  ushort* h1b    = (ushort*)(ws + OFF_H1B);
  float*  wT_ih0 = (float*) (ws + OFF_WTIH0);
  float*  xproj  = (float*) (ws + OFF_XPROJ);
  int*    bar    = (int*)   (ws + OFF_BAR);
  int*    ord    = (int*)   (ws + OFF_ORD);
  int*    gmax   = (int*)   (ws + OFF_GMAX);
  (void)in_sizes; (void)n_in; (void)out_size; (void)ws_size; (void)WS_NEED;

  hipLaunchKernelGGL(k_prep, dim3(1), dim3(256), 0, stream,
                     ns, que, b_ih0, b_hh0, b_ih1, b_hh1,
                     Lp, maxLp, map, bias0, bias1, c0, c1, hlast, h0b, h1b, bar,
                     ord, gmax);

  hipLaunchKernelGGL(k_transpose, dim3(64, 24), dim3(32, 8), 0, stream,
                     w_ih0, wT_ih0);

  hipLaunchKernelGGL(k_proj, dim3(81, 16), dim3(128), 0, stream,
                     text, ques, code, wT_ih0, bias0, xproj);

  const float* a_whh0 = w_hh0; const float* a_wih1 = w_ih1; const float* a_whh1 = w_hh1;
  const float* a_xp = xproj;   const float* a_b1 = bias1;
  const int* a_Lp = Lp; const int* a_gmax = gmax; const int* a_map = map;
  const int* a_ord = ord;
  ushort* a_h0b = h0b; ushort* a_h1b = h1b; float* a_c0 = c0; float* a_c1 = c1;
  float* a_hl = hlast; const float* a_fcw = fcw; const float* a_fcb = fcb;
  float* a_out = out; int* a_bar = bar;
  void* args[] = { &a_whh0, &a_wih1, &a_whh1, &a_xp, &a_b1, &a_Lp, &a_gmax, &a_map,
                   &a_ord, &a_h0b, &a_h1b, &a_c0, &a_c1, &a_hl, &a_fcw, &a_fcb,
                   &a_out, &a_bar };

  hipError_t err = hipLaunchCooperativeKernel((const void*)k_lstm_coop,
                                              dim3(128), dim3(256), args, 0, stream);
  if (err != hipSuccess) {
    (void)hipGetLastError();  // clear error state
    for (int t = 0; t < S_ + 1; ++t) {
      hipLaunchKernelGGL(k_step, dim3(128), dim3(256), 0, stream, t,
                         w_hh0, w_ih1, w_hh1, xproj, bias1, Lp, gmax, map, ord,
                         h0b, h1b, c0, c1, hlast);
    }
    hipLaunchKernelGGL(k_fc, dim3(1), dim3(128), 0, stream, hlast, fcw, fcb, out);
  }
}

// Round 13
// 2240.728 us; speedup vs baseline: 1.8747x; 1.8747x over previous
//
#include <hip/hip_runtime.h>
#include <hip/hip_cooperative_groups.h>

namespace cg = cooperative_groups;

#define B_    64
#define Q_    16
#define MAXK_ 32
#define C_    64
#define D_    768
#define H_    512
#define G4_   2048   // 4*H
#define S_    529    // Q*(MAXK+1)+1
#define NR_   81     // 16 questions + 64 code + 1 text

typedef float f32x4_t __attribute__((ext_vector_type(4)));
typedef unsigned int u32x2_t __attribute__((ext_vector_type(2)));
typedef unsigned int u32x4_t __attribute__((ext_vector_type(4)));
typedef _Float16 f16x8_t __attribute__((ext_vector_type(8)));

// ---------------- workspace layout (bytes) ----------------
static constexpr size_t OFF_L     = 0;                      // 64 int
static constexpr size_t OFF_MAXL  = 256;
static constexpr size_t OFF_MAP   = 512;                    // 64*529*4
static constexpr size_t OFF_BIAS0 = OFF_MAP   + 135424;     // 2048 f
static constexpr size_t OFF_BIAS1 = OFF_BIAS0 + 8192;       // 2048 f
static constexpr size_t OFF_C0    = OFF_BIAS1 + 8192;       // 64*512 f
static constexpr size_t OFF_C1    = OFF_C0    + 131072;
static constexpr size_t OFF_HLAST = OFF_C1    + 131072;     // 64*512 f (fp32, real-batch idx)
static constexpr size_t OFF_H0B   = OFF_HLAST + 131072;     // 2 x 64*512 half (sorted idx)
static constexpr size_t OFF_H1B   = OFF_H0B   + 262144;
static constexpr size_t OFF_WTIH0 = OFF_H1B   + 262144;     // 768x2048 f
static constexpr size_t OFF_XPROJ = OFF_WTIH0 + 6291456ULL; // 64*81*2048 f
static constexpr size_t OFF_BAR   = OFF_XPROJ + 42467328ULL; // 4 groups x 64 int
static constexpr size_t OFF_ORD   = OFF_BAR   + 4096;       // 64 int (sorted batch ids)
static constexpr size_t OFF_GMAX  = OFF_ORD   + 256;        // 4 int (per-group max L)
static constexpr size_t WS_NEED   = OFF_GMAX  + 256;

// group g owns sorted ranks [gbase, gbase+16)
__device__ __forceinline__ int group_base(int g) {
  return (g == 0) ? 0 : (g == 1) ? 16 : (g == 2) ? 48 : 32;
}

// ---------------- coherent (L2-bypass) access helpers ----------------
__device__ __forceinline__ void store_us_cc(ushort* p, unsigned int v) {
  asm volatile("global_store_short %0, %1, off sc0 sc1" :: "v"(p), "v"(v) : "memory");
}
__device__ __forceinline__ void store_f_cc(float* p, float v) {
  asm volatile("global_store_dword %0, %1, off sc0 sc1" :: "v"(p), "v"(v) : "memory");
}
__device__ __forceinline__ void load_a_cc(u32x4_t& v, const ushort* p) {
  asm volatile("global_load_dwordx4 %0, %1, off sc0 sc1" : "=v"(v) : "v"(p) : "memory");
}

__device__ __forceinline__ unsigned int pkrtz(float a, float b) {
  auto r = __builtin_amdgcn_cvt_pkrtz(a, b);
  unsigned int u;
  __builtin_memcpy(&u, &r, 4);
  return u;
}
__device__ __forceinline__ unsigned int f2h(float a) {
  return pkrtz(a, 0.f) & 0xffffu;
}
__device__ __forceinline__ f32x4_t mfma16(u32x4_t a, u32x4_t b, f32x4_t c) {
  f16x8_t av, bv;
  __builtin_memcpy(&av, &a, 16);
  __builtin_memcpy(&bv, &b, 16);
  return __builtin_amdgcn_mfma_f32_16x16x32_f16(av, bv, c, 0, 0, 0);
}

__device__ __forceinline__ float sigm(float x) { return 1.f/(1.f + __expf(-x)); }
// fast tanh: 1 - 2/(e^{2x}+1); correct limits at +/-inf
__device__ __forceinline__ float tanh_fast(float x) {
  return 1.f - 2.f/(__expf(2.f*x) + 1.f);
}

// P-partials LDS geometry: P[wl=wv*2+layer][col=64][m=16] with col stride 20
#define PSEG 1280              // 64*20 floats per wl
#define PCOL 20

// ---------------- prep ----------------
__global__ __launch_bounds__(256) void k_prep(
    const int* __restrict__ ns, const int* __restrict__ que,
    const float* __restrict__ b_ih0, const float* __restrict__ b_hh0,
    const float* __restrict__ b_ih1, const float* __restrict__ b_hh1,
    int* __restrict__ Lp, int* __restrict__ maxLp, int* __restrict__ map,
    float* __restrict__ bias0, float* __restrict__ bias1,
    float* __restrict__ c0, float* __restrict__ c1, float* __restrict__ hlast,
    ushort* __restrict__ h0b, ushort* __restrict__ h1b, int* __restrict__ bar,
    int* __restrict__ ord, int* __restrict__ gmax)
{
  const int tid = threadIdx.x;
  for (int i = tid; i < B_*S_; i += 256) map[i] = -1;
  for (int i = tid; i < G4_; i += 256) {
    bias0[i] = b_ih0[i] + b_hh0[i];
    bias1[i] = b_ih1[i] + b_hh1[i];
  }
  int* h0i = (int*)h0b;
  int* h1i = (int*)h1b;
  for (int i = tid; i < B_*H_; i += 256) {
    c0[i]=0.f; c1[i]=0.f; hlast[i]=0.f;
    h0i[i]=0; h1i[i]=0;
  }
  for (int i = tid; i < 1024; i += 256) bar[i] = 0;
  if (tid == 0) *maxLp = 0;
  __syncthreads();
  if (tid < B_) {
    const int b = tid;
    const int qn = que[b];
    int pos = 0;
    int* m = map + b*S_;
    for (int q = 0; q < qn; ++q) {
      m[pos++] = q;
      const int n = ns[b*Q_ + q];
      for (int k = 0; k < n; ++k) {
        int j = q + k; if (j > C_-1) j = C_-1;
        m[pos++] = 16 + j;
      }
    }
    m[pos] = 80;
    Lp[b] = pos;
    atomicMax(maxLp, pos);
  }
  __syncthreads();
  if (tid < B_) {
    const int myL = Lp[tid];
    int rank = 0;
    for (int j = 0; j < B_; ++j) {
      const int lj = Lp[j];
      rank += (lj > myL) || (lj == myL && j < tid);
    }
    ord[rank] = tid;
  }
  __syncthreads();
  if (tid < 4) {
    const int gb = (tid == 0) ? 0 : (tid == 1) ? 16 : (tid == 2) ? 48 : 32;
    gmax[tid] = Lp[ord[gb]];
  }
}

// ---------------- transpose W_ih0 only ----------------
__global__ __launch_bounds__(256) void k_transpose(
    const float* __restrict__ w, float* __restrict__ wT)
{
  __shared__ float tile[32][33];
  const int n0 = blockIdx.x * 32;
  const int k0 = blockIdx.y * 32;
  const int tx = threadIdx.x, ty = threadIdx.y;
  for (int i = ty; i < 32; i += 8)
    tile[i][tx] = w[(size_t)(n0+i)*D_ + k0 + tx];
  __syncthreads();
  for (int i = ty; i < 32; i += 8)
    wT[(size_t)(k0 + i)*G4_ + n0 + tx] = tile[tx][i];
}

// ---------------- xproj ----------------
__global__ __launch_bounds__(128, 2) void k_proj(
    const float* __restrict__ text, const float* __restrict__ ques,
    const float* __restrict__ code, const float* __restrict__ wT_ih0,
    const float* __restrict__ bias0, float* __restrict__ xproj)
{
  __shared__ float hsLds[32][64];
  const int mb = blockIdx.x, nb = blockIdx.y;
  const int n0 = nb * 128;
  const int tid = threadIdx.x;
  const int tb = tid >> 4, tn = tid & 15;
  const int b0 = tb * 8;
  const int bb = tid >> 1, hh = tid & 1;

  const int mrow = mb*64 + bb;
  const int sb = mrow / NR_, sr = mrow % NR_;
  const float* srcrow = (sr < 16) ? (ques + ((size_t)sb*Q_ + sr)*D_)
                      : (sr < 80) ? (code + ((size_t)sb*C_ + (sr-16))*D_)
                                  : (text + (size_t)sb*D_);

  float a[8][8];
  #pragma unroll
  for (int i=0;i<8;i++)
    #pragma unroll
    for (int j=0;j<8;j++) a[i][j]=0.f;

  for (int k0 = 0; k0 < D_; k0 += 32) {
    __syncthreads();
    {
      const float* p = srcrow + k0 + hh*16;
      float4 v0 = *(const float4*)(p+0);
      float4 v1 = *(const float4*)(p+4);
      float4 v2 = *(const float4*)(p+8);
      float4 v3 = *(const float4*)(p+12);
      const int kk = hh*16;
      hsLds[kk+ 0][bb]=v0.x; hsLds[kk+ 1][bb]=v0.y; hsLds[kk+ 2][bb]=v0.z; hsLds[kk+ 3][bb]=v0.w;
      hsLds[kk+ 4][bb]=v1.x; hsLds[kk+ 5][bb]=v1.y; hsLds[kk+ 6][bb]=v1.z; hsLds[kk+ 7][bb]=v1.w;
      hsLds[kk+ 8][bb]=v2.x; hsLds[kk+ 9][bb]=v2.y; hsLds[kk+10][bb]=v2.z; hsLds[kk+11][bb]=v2.w;
      hsLds[kk+12][bb]=v3.x; hsLds[kk+13][bb]=v3.y; hsLds[kk+14][bb]=v3.z; hsLds[kk+15][bb]=v3.w;
    }
    __syncthreads();
    const float* wb = wT_ih0 + (size_t)k0*G4_ + n0 + tn*8;
    #pragma unroll 4
    for (int k=0;k<32;k++){
      float4 w0 = *(const float4*)(wb + (size_t)k*G4_);
      float4 w1 = *(const float4*)(wb + (size_t)k*G4_ + 4);
      float4 hA = *(const float4*)(&hsLds[k][b0]);
      float4 hB = *(const float4*)(&hsLds[k][b0+4]);
      float hv[8]={hA.x,hA.y,hA.z,hA.w,hB.x,hB.y,hB.z,hB.w};
      float wv[8]={w0.x,w0.y,w0.z,w0.w,w1.x,w1.y,w1.z,w1.w};
      #pragma unroll
      for (int i=0;i<8;i++)
        #pragma unroll
        for (int j=0;j<8;j++)
          a[i][j] = fmaf(hv[i], wv[j], a[i][j]);
    }
  }
  float bz[8];
  #pragma unroll
  for (int j=0;j<8;j++) bz[j] = bias0[n0 + tn*8 + j];
  #pragma unroll
  for (int i=0;i<8;i++){
    const int m = mb*64 + b0 + i;
    float* pd = xproj + (size_t)m*G4_ + n0 + tn*8;
    *(float4*)(pd+0) = make_float4(a[i][0]+bz[0], a[i][1]+bz[1], a[i][2]+bz[2], a[i][3]+bz[3]);
    *(float4*)(pd+4) = make_float4(a[i][4]+bz[4], a[i][5]+bz[5], a[i][6]+bz[6], a[i][7]+bz[7]);
  }
}

// ---------------- persistent LSTM (MFMA core, fat blocks) ----------------
// 128 blocks: g = blk>>5, us = blk&31 (16 units -> N=64 cols/layer).
__device__ __forceinline__ void load_wfrags(int tid, int us,
    const float* __restrict__ w_hh0, const float* __restrict__ w_ih1,
    const float* __restrict__ w_hh1, u32x4_t* wf0, u32x4_t* wf1)
{
  const int wv = tid >> 6, lane = tid & 63;
  const int nidx = lane & 15, kgrp = lane >> 4;
  #pragma unroll
  for (int nt = 0; nt < 4; ++nt) {
    const int ngl = (nidx >> 2)*H_ + us*16 + nt*4 + (nidx & 3);
    const float* r0 = w_hh0 + (size_t)ngl*H_ + wv*128 + kgrp*8;
    #pragma unroll
    for (int f = 0; f < 4; ++f) {
      float4 lo = *(const float4*)(r0 + f*32);
      float4 hi = *(const float4*)(r0 + f*32 + 4);
      wf0[nt*4+f] = (u32x4_t){pkrtz(lo.x,lo.y), pkrtz(lo.z,lo.w), pkrtz(hi.x,hi.y), pkrtz(hi.z,hi.w)};
    }
    const float* w1 = (wv < 2) ? w_ih1 : w_hh1;
    const float* r1 = w1 + (size_t)ngl*H_ + (wv & 1)*256 + kgrp*8;
    #pragma unroll
    for (int f = 0; f < 8; ++f) {
      float4 lo = *(const float4*)(r1 + f*32);
      float4 hi = *(const float4*)(r1 + f*32 + 4);
      wf1[nt*8+f] = (u32x4_t){pkrtz(lo.x,lo.y), pkrtz(lo.z,lo.w), pkrtz(hi.x,hi.y), pkrtz(hi.z,hi.w)};
    }
  }
}

__device__ __forceinline__ void xg_prefetch(int t, int maxLg,
    const int* __restrict__ mrow, const float* __restrict__ xbase,
    float& xg0, float& xg1, float& xg2, float& xg3, int& rpre)
{
  rpre = (t <= maxLg) ? mrow[t] : -1;
  const float* xp = xbase + (size_t)(rpre < 0 ? 0 : rpre)*G4_;
  xg0 = xp[0]; xg1 = xp[512]; xg2 = xp[1024]; xg3 = xp[1536];
}

__device__ __forceinline__ void lstm_iter(int t, int maxLg, int gbase, int us,
    const u32x4_t* wf0, const u32x4_t* wf1, float* __restrict__ P,
    const ushort* __restrict__ h0c, ushort* __restrict__ h0n,
    const ushort* __restrict__ h1c, ushort* __restrict__ h1n,
    float* __restrict__ c0, float* __restrict__ c1, float* __restrict__ hlast,
    const int* __restrict__ mrow, const float* __restrict__ xbase,
    float& xg0, float& xg1, float& xg2, float& xg3, int& rpre0, int& rpre1,
    float b1v0, float b1v1, float b1v2, float b1v3, int Lrb, int rb)
{
  const int tid = threadIdx.x;
  const int wv = tid >> 6, lane = tid & 63;
  const int nidx = lane & 15, kgrp = lane >> 4;

  // ---- A-fragment loads (h through LLC), first thing after release ----
  u32x4_t a0[4], a1[8];
  {
    const ushort* h0r = h0c + (size_t)(gbase + nidx)*H_ + wv*128 + kgrp*8;
    #pragma unroll
    for (int f = 0; f < 4; ++f) load_a_cc(a0[f], h0r + f*32);
    const ushort* hs1 = (wv < 2) ? h0c : h1c;
    const ushort* h1r = hs1 + (size_t)(gbase + nidx)*H_ + (wv & 1)*256 + kgrp*8;
    #pragma unroll
    for (int f = 0; f < 8; ++f) load_a_cc(a1[f], h1r + f*32);
  }
  asm volatile("s_waitcnt vmcnt(0)" ::: "memory");
  __builtin_amdgcn_sched_barrier(0);   // rule #18: keep MFMAs below the wait

  f32x4_t acc0[4], acc1[4];
  #pragma unroll
  for (int nt = 0; nt < 4; ++nt) { acc0[nt] = (f32x4_t){0.f,0.f,0.f,0.f}; acc1[nt] = (f32x4_t){0.f,0.f,0.f,0.f}; }
  #pragma unroll
  for (int nt = 0; nt < 4; ++nt)
    #pragma unroll
    for (int f = 0; f < 4; ++f) acc0[nt] = mfma16(a0[f], wf0[nt*4+f], acc0[nt]);
  #pragma unroll
  for (int nt = 0; nt < 4; ++nt)
    #pragma unroll
    for (int f = 0; f < 8; ++f) acc1[nt] = mfma16(a1[f], wf1[nt*8+f], acc1[nt]);

  // ---- stash per-wave partials ----
  #pragma unroll
  for (int nt = 0; nt < 4; ++nt) {
    *(f32x4_t*)(P + (wv*2+0)*PSEG + (nt*16 + nidx)*PCOL + kgrp*4) = acc0[nt];
    *(f32x4_t*)(P + (wv*2+1)*PSEG + (nt*16 + nidx)*PCOL + kgrp*4) = acc1[nt];
  }

  // ---- prefetch NEXT step's gate context (off critical path) ----
  float nxg0=xg0, nxg1=xg1, nxg2=xg2, nxg3=xg3;
  int nr0 = -1;
  const int nr1 = rpre0;
  xg_prefetch(t + 1, maxLg, mrow, xbase, nxg0, nxg1, nxg2, nxg3, nr0);
  __syncthreads();     // cross-wave P visibility

  // ---- gates: every thread does one L0 cell and one L1 cell ----
  const int bl = tid & 15, ul = tid >> 4;
  const int pb = gbase + bl;
  const int u = us*16 + ul;
  const int idx = pb*H_ + u;
  const int clb = (ul >> 2)*16 + (ul & 3);
  if (rpre0 >= 0) {
    float g0=xg0, g1=xg1, g2=xg2, g3=xg3;
    #pragma unroll
    for (int w = 0; w < 4; ++w) {
      const float* Pr = P + (w*2+0)*PSEG + bl;
      g0 += Pr[(clb+ 0)*PCOL]; g1 += Pr[(clb+ 4)*PCOL];
      g2 += Pr[(clb+ 8)*PCOL]; g3 += Pr[(clb+12)*PCOL];
    }
    const float cc = sigm(g1)*c0[idx] + sigm(g0)*tanh_fast(g2);
    c0[idx] = cc;
    store_us_cc(h0n + idx, f2h(sigm(g3)*tanh_fast(cc)));
  }
  if (rpre1 >= 0) {
    float g0=b1v0, g1=b1v1, g2=b1v2, g3=b1v3;
    #pragma unroll
    for (int w = 0; w < 4; ++w) {
      const float* Pr = P + (w*2+1)*PSEG + bl;
      g0 += Pr[(clb+ 0)*PCOL]; g1 += Pr[(clb+ 4)*PCOL];
      g2 += Pr[(clb+ 8)*PCOL]; g3 += Pr[(clb+12)*PCOL];
    }
    const float cc = sigm(g1)*c1[idx] + sigm(g0)*tanh_fast(g2);
    c1[idx] = cc;
    const float hn = sigm(g3)*tanh_fast(cc);
    store_us_cc(h1n + idx, f2h(hn));
    if (t - 1 == Lrb) store_f_cc(hlast + rb*H_ + u, hn);
  }

  xg0 = nxg0; xg1 = nxg1; xg2 = nxg2; xg3 = nxg3;
  rpre0 = nr0; rpre1 = nr1;
}

// ---------------- per-group barrier (round-11 form): single counter, thread-0 poll ----------------
__device__ __forceinline__ void grid_barrier_g(int* __restrict__ cnt, int gen)
{
  asm volatile("s_waitcnt vmcnt(0)" ::: "memory");
  __syncthreads();
  if (threadIdx.x == 0) {
    atomicAdd(cnt, 1);
    while (__hip_atomic_load(cnt, __ATOMIC_RELAXED, __HIP_MEMORY_SCOPE_AGENT) < gen*32)
      __builtin_amdgcn_s_sleep(1);
  }
  __syncthreads();
}

// ---------------- cooperative persistent kernel ----------------
__global__ __launch_bounds__(256, 1) void k_lstm_coop(
    const float* __restrict__ w_hh0, const float* __restrict__ w_ih1,
    const float* __restrict__ w_hh1, const float* __restrict__ xproj,
    const float* __restrict__ bias1, const int* __restrict__ Lp,
    const int* __restrict__ gmax, const int* __restrict__ map,
    const int* __restrict__ ord,
    ushort* __restrict__ h0b, ushort* __restrict__ h1b,
    float* __restrict__ c0, float* __restrict__ c1, float* __restrict__ hlast,
    const float* __restrict__ fcw, const float* __restrict__ fcb,
    float* __restrict__ out, int* __restrict__ bar)
{
  __shared__ __align__(16) float P[8*PSEG];
  const int blk = blockIdx.x;
  const int g = blk >> 5, us = blk & 31;
  const int gbase = group_base(g);
  const int tid = threadIdx.x;

  u32x4_t wf0[16], wf1[32];
  load_wfrags(tid, us, w_hh0, w_ih1, w_hh1, wf0, wf1);
  const int maxLg = gmax[g];
  int* cnt = bar + g*64;

  const int rb = ord[gbase + (tid & 15)];
  const int* mrow = map + rb*S_;
  const int u = us*16 + (tid >> 4);
  const float* xbase = xproj + (size_t)rb*NR_*G4_ + u;
  const float b1v0 = bias1[u], b1v1 = bias1[512+u], b1v2 = bias1[1024+u], b1v3 = bias1[1536+u];
  const int Lrb = Lp[rb];

  float xg0=0.f, xg1=0.f, xg2=0.f, xg3=0.f;
  int rpre0 = -1, rpre1 = -1;
  xg_prefetch(0, maxLg, mrow, xbase, xg0, xg1, xg2, xg3, rpre0);
  __syncthreads();

  for (int t = 0; t <= maxLg + 1; ++t) {
    const ushort* h0c = h0b + (size_t)(t & 1)*(B_*H_);
    ushort*       h0n = h0b + (size_t)((t+1) & 1)*(B_*H_);
    const ushort* h1c = h1b + (size_t)(t & 1)*(B_*H_);
    ushort*       h1n = h1b + (size_t)((t+1) & 1)*(B_*H_);
    lstm_iter(t, maxLg, gbase, us, wf0, wf1, P,
              h0c, h0n, h1c, h1n, c0, c1, hlast,
              mrow, xbase, xg0, xg1, xg2, xg3, rpre0, rpre1,
              b1v0, b1v1, b1v2, b1v3, Lrb, rb);
    grid_barrier_g(cnt, t + 1);
  }
  // ---- per-group FC epilogue ----
  if (us == 0 && tid < 32) {
    const int pb = gbase + (tid >> 1), half = tid & 1;
    const int rbf = ord[pb];
    const float* hv = hlast + (size_t)rbf*H_ + half*256;
    const float* fw = fcw + half*256;
    float s = 0.f;
    #pragma unroll 8
    for (int uu = 0; uu < 256; ++uu) s = fmaf(hv[uu], fw[uu], s);
    s += __shfl_xor(s, 1);
    if (half == 0) store_f_cc(out + rbf, s + fcb[0]);
  }
}

// ---------------- non-cooperative fallback: one iteration per launch ----------------
__global__ __launch_bounds__(256, 1) void k_step(int t,
    const float* __restrict__ w_hh0, const float* __restrict__ w_ih1,
    const float* __restrict__ w_hh1, const float* __restrict__ xproj,
    const float* __restrict__ bias1, const int* __restrict__ Lp,
    const int* __restrict__ gmax, const int* __restrict__ map,
    const int* __restrict__ ord,
    ushort* __restrict__ h0b, ushort* __restrict__ h1b,
    float* __restrict__ c0, float* __restrict__ c1, float* __restrict__ hlast)
{
  __shared__ __align__(16) float P[8*PSEG];
  const int blk = blockIdx.x;
  const int g = blk >> 5, us = blk & 31;
  const int gbase = group_base(g);
  const int maxLg = gmax[g];
  if (t > maxLg + 1) return;
  const int tid = threadIdx.x;
  u32x4_t wf0[16], wf1[32];
  load_wfrags(tid, us, w_hh0, w_ih1, w_hh1, wf0, wf1);

  const int rb = ord[gbase + (tid & 15)];
  const int* mrow = map + rb*S_;
  const int u = us*16 + (tid >> 4);
  const float* xbase = xproj + (size_t)rb*NR_*G4_ + u;
  const float b1v0 = bias1[u], b1v1 = bias1[512+u], b1v2 = bias1[1024+u], b1v3 = bias1[1536+u];
  const int Lrb = Lp[rb];

  float xg0=0.f, xg1=0.f, xg2=0.f, xg3=0.f;
  int rpre0 = -1, rpre1 = -1;
  xg_prefetch(t, maxLg, mrow, xbase, xg0, xg1, xg2, xg3, rpre0);
  rpre1 = (t-1 >= 0 && t-1 <= maxLg) ? mrow[t-1] : -1;
  __syncthreads();

  const ushort* h0c = h0b + (size_t)(t & 1)*(B_*H_);
  ushort*       h0n = h0b + (size_t)((t+1) & 1)*(B_*H_);
  const ushort* h1c = h1b + (size_t)(t & 1)*(B_*H_);
  ushort*       h1n = h1b + (size_t)((t+1) & 1)*(B_*H_);
  lstm_iter(t, maxLg, gbase, us, wf0, wf1, P,
            h0c, h0n, h1c, h1n, c0, c1, hlast,
            mrow, xbase, xg0, xg1, xg2, xg3, rpre0, rpre1,
            b1v0, b1v1, b1v2, b1v3, Lrb, rb);
}

__global__ __launch_bounds__(128) void k_fc(
    const float* __restrict__ hlast, const float* __restrict__ fcw,
    const float* __restrict__ fcb, float* __restrict__ out)
{
  const int tid = threadIdx.x;
  if (tid < 128) {
    const int b = tid >> 1, half = tid & 1;
    const float* hv = hlast + (size_t)b*H_ + half*256;
    const float* fw = fcw + half*256;
    float s = 0.f;
    #pragma unroll 8
    for (int u = 0; u < 256; ++u) s = fmaf(hv[u], fw[u], s);
    s += __shfl_xor(s, 1);
    if (half == 0) out[b] = s + fcb[0];
  }
}

// ---------------- host ----------------
extern "C" void kernel_launch(void* const* d_in, const int* in_sizes, int n_in,
                              void* d_out, int out_size, void* d_ws, size_t ws_size,
                              hipStream_t stream)
{
  const float* text  = (const float*)d_in[0];
  const float* ques  = (const float*)d_in[1];
  const float* code  = (const float*)d_in[2];
  const int*   ns    = (const int*)  d_in[3];
  const int*   que   = (const int*)  d_in[4];
  const float* w_ih0 = (const float*)d_in[5];
  const float* w_hh0 = (const float*)d_in[6];
  const float* b_ih0 = (const float*)d_in[7];
  const float* b_hh0 = (const float*)d_in[8];
  const float* w_ih1 = (const float*)d_in[9];
  const float* w_hh1 = (const float*)d_in[10];
  const float* b_ih1 = (const float*)d_in[11];
  const float* b_hh1 = (const float*)d_in[12];
  const float* fcw   = (const float*)d_in[13];
  const float* fcb   = (const float*)d_in[14];
  float* out = (float*)d_out;

  char* ws = (char*)d_ws;
  int*    Lp     = (int*)   (ws + OFF_L);
  int*    maxLp  = (int*)   (ws + OFF_MAXL);
  int*    map    = (int*)   (ws + OFF_MAP);
  float*  bias0  = (float*) (ws + OFF_BIAS0);
  float*  bias1  = (float*) (ws + OFF_BIAS1);
  float*  c0     = (float*) (ws + OFF_C0);
  float*  c1     = (float*) (ws + OFF_C1);
  float*  hlast  = (float*) (ws + OFF_HLAST);
  ushort* h0b    = (ushort*)(ws + OFF_H0B);
  ushort* h1b    = (ushort*)(ws + OFF_H1B);
  float*  wT_ih0 = (float*) (ws + OFF_WTIH0);
  float*  xproj  = (float*) (ws + OFF_XPROJ);
  int*    bar    = (int*)   (ws + OFF_BAR);
  int*    ord    = (int*)   (ws + OFF_ORD);
  int*    gmax   = (int*)   (ws + OFF_GMAX);
  (void)in_sizes; (void)n_in; (void)out_size; (void)ws_size; (void)WS_NEED;

  hipLaunchKernelGGL(k_prep, dim3(1), dim3(256), 0, stream,
                     ns, que, b_ih0, b_hh0, b_ih1, b_hh1,
                     Lp, maxLp, map, bias0, bias1, c0, c1, hlast, h0b, h1b, bar,
                     ord, gmax);

  hipLaunchKernelGGL(k_transpose, dim3(64, 24), dim3(32, 8), 0, stream,
                     w_ih0, wT_ih0);

  hipLaunchKernelGGL(k_proj, dim3(81, 16), dim3(128), 0, stream,
                     text, ques, code, wT_ih0, bias0, xproj);

  const float* a_whh0 = w_hh0; const float* a_wih1 = w_ih1; const float* a_whh1 = w_hh1;
  const float* a_xp = xproj;   const float* a_b1 = bias1;
  const int* a_Lp = Lp; const int* a_gmax = gmax; const int* a_map = map;
  const int* a_ord = ord;
  ushort* a_h0b = h0b; ushort* a_h1b = h1b; float* a_c0 = c0; float* a_c1 = c1;
  float* a_hl = hlast; const float* a_fcw = fcw; const float* a_fcb = fcb;
  float* a_out = out; int* a_bar = bar;
  void* args[] = { &a_whh0, &a_wih1, &a_whh1, &a_xp, &a_b1, &a_Lp, &a_gmax, &a_map,
                   &a_ord, &a_h0b, &a_h1b, &a_c0, &a_c1, &a_hl, &a_fcw, &a_fcb,
                   &a_out, &a_bar };

  hipError_t err = hipLaunchCooperativeKernel((const void*)k_lstm_coop,
                                              dim3(128), dim3(256), args, 0, stream);
  if (err != hipSuccess) {
    (void)hipGetLastError();  // clear error state
    for (int t = 0; t < S_ + 1; ++t) {
      hipLaunchKernelGGL(k_step, dim3(128), dim3(256), 0, stream, t,
                         w_hh0, w_ih1, w_hh1, xproj, bias1, Lp, gmax, map, ord,
                         h0b, h1b, c0, c1, hlast);
    }
    hipLaunchKernelGGL(k_fc, dim3(1), dim3(128), 0, stream, hlast, fcw, fcb, out);
  }
}